// Round 5
// baseline (184.672 us; speedup 1.0000x reference)
//
#include <hip/hip_runtime.h>
#include <math.h>

// EulerRosenbrockModel: B=512, D=256, HID=1024, h=0.01
// out = v + 0.005 * W2 (s ⊙ (W1 vb)),  s = 1-t^2, t = tanh(W1 y + b1), v = W2 t + b2
// (Neumann truncation of (I-cJ)^{-1}(I+dJ), exact to ~1e-5 — verified R1-R11.)
//
// R12: SINGLE DISPATCH. R11 post-mortem: fused fell under 40us, leaving
// ~35-40us of dispatch-boundary overhead across 2 dispatches — the boundary
// now costs as much as the kernel. Also: 1024-thr blocks hard-cap VGPR at
// 128 (R10's WRITE_SIZE=24MB vs 0.5MB output = scratch spill traffic).
// Fixes:
//   * one kernel: waves load W1/W2 fragments DIRECTLY from the original fp32
//     layout (lane l: rows tile*16+(l&15), cols ks*32+quad*8; 16x128B
//     segments per fragment) and convert fp32->bf16 in registers (same RNE
//     bit-trick as the old convert_w -> bitwise-identical math).
//   * 512 threads (8 waves) -> 256-VGPR budget: depth-8-fragment double
//     buffer (128 VGPR raw fp32) fits with NO spill; 16-32KB in flight/wave.
//   * raw lgkm-only barriers (4 total) + cross-phase prefetch (R11-verified).
// Per-CU stream 4MB fp32 -> port floor ~27us; conversion VALU hides under it.

#define B_SZ 512
#define D_SZ 256
#define HID_SZ 1024

typedef short short8 __attribute__((ext_vector_type(8)));   // 8 bf16 (4 VGPRs)
typedef float f32x4 __attribute__((ext_vector_type(4)));

__device__ __forceinline__ float bf16_to_f32(unsigned short u) {
    union { unsigned int i; float f; } c; c.i = ((unsigned int)u) << 16; return c.f;
}
__device__ __forceinline__ unsigned short f32_to_bf16(float f) {
    union { float f; unsigned int i; } c; c.f = f;
    unsigned int b = c.i + 0x7FFFu + ((c.i >> 16) & 1u);   // RNE
    return (unsigned short)(b >> 16);
}
__device__ __forceinline__ uint4 pack8(float4 lo, float4 hi) {
    union { unsigned short u[8]; uint4 v; } o;
    o.u[0] = f32_to_bf16(lo.x); o.u[1] = f32_to_bf16(lo.y);
    o.u[2] = f32_to_bf16(lo.z); o.u[3] = f32_to_bf16(lo.w);
    o.u[4] = f32_to_bf16(hi.x); o.u[5] = f32_to_bf16(hi.y);
    o.u[6] = f32_to_bf16(hi.z); o.u[7] = f32_to_bf16(hi.w);
    return o.v;
}
__device__ __forceinline__ short8 as_short8(uint4 u) {
    union { uint4 v; short8 s; } c; c.v = u; return c.s;
}
__device__ __forceinline__ float fast_tanh(float x) {
    float e = __expf(2.0f * x);
    return 1.0f - 2.0f / (e + 1.0f);
}
// lgkm-drain barrier: cross-wave LDS visibility WITHOUT draining vmcnt —
// global loads stay in flight across it (R9/R11-verified correct).
__device__ __forceinline__ void bar_lgkm() {
    asm volatile("s_waitcnt lgkmcnt(0)" ::: "memory");
    __builtin_amdgcn_s_barrier();
    asm volatile("" ::: "memory");
}

// ---- fused chain, ONE dispatch. 32 blocks x 512 thr (8 waves), 16 rows/block.
// ph0/ph2: wave owns 8 hid tiles (cols wid*128..+128).
// ph1/ph3: wave owns 2 out tiles (cols wid*32..+32), K=1024 (4 groups/tile).
__global__ __launch_bounds__(512, 2)
void fused_chain(const float* __restrict__ Y,
                 const float* __restrict__ W1,
                 const float* __restrict__ b1,
                 const float* __restrict__ W2,
                 const float* __restrict__ b2,
                 float* __restrict__ OUT)
{
    __shared__ alignas(16) unsigned short Av[16][264];   //  8.3 KB  Y bf16, then vb
    __shared__ alignas(16) unsigned short T[16][1032];   // 32.3 KB  t, then p
    __shared__ alignas(16) float V[16][264];             // 16.5 KB  v fp32  (57 KB)

    const int tid  = threadIdx.x;
    const int wid  = tid >> 6, lane = tid & 63;          // wid 0..7
    const int l16  = lane & 15, quad = lane >> 4;
    const int bm   = blockIdx.x * 16;

    // per-lane fragment bases (original fp32 layouts)
    const float* w1base = W1 + (size_t)l16 * D_SZ  + quad * 8;   // row-stride 256 f
    const float* w2base = W2 + (size_t)l16 * HID_SZ + quad * 8;  // row-stride 1024 f

    float4 rawE[16], rawO[16];   // depth-8-fragment double buffer (64+64 VGPR)

    // 8 fragments (one W1 tile, K=256) of tile (wid*8 + T_) -> BUF
#define LDW1(BUF, T_) do {                                                    \
        const float* p_ = w1base + (size_t)(wid * 8 + (T_)) * (16 * D_SZ);    \
        _Pragma("unroll")                                                     \
        for (int k = 0; k < 8; ++k) {                                         \
            BUF[2*k]   = *(const float4*)(p_ + k * 32);                       \
            BUF[2*k+1] = *(const float4*)(p_ + k * 32 + 4);                   \
        } } while (0)

    // 8 fragments (quarter-K group G_ of W2 tile wid*2 + T2_) -> BUF
#define LDW2(BUF, T2_, G_) do {                                               \
        const float* p_ = w2base + (size_t)(wid * 2 + (T2_)) * (16 * HID_SZ)  \
                          + (G_) * 256;                                       \
        _Pragma("unroll")                                                     \
        for (int k = 0; k < 8; ++k) {                                         \
            BUF[2*k]   = *(const float4*)(p_ + k * 32);                       \
            BUF[2*k+1] = *(const float4*)(p_ + k * 32 + 4);                   \
        } } while (0)

#define FR(BUF, K) as_short8(pack8(BUF[2*(K)], BUF[2*(K)+1]))

    // ph0/ph2 tile: 8 MFMAs vs A-regs
#define MFW1(BUF) do { acc = (f32x4){0.f,0.f,0.f,0.f};                        \
        _Pragma("unroll")                                                     \
        for (int k = 0; k < 8; ++k)                                           \
            acc = __builtin_amdgcn_mfma_f32_16x16x32_bf16(a0[k], FR(BUF, k),  \
                                                          acc, 0, 0, 0);      \
        } while (0)

    // ph1/ph3 group: 8 MFMAs, A from T LDS, accumulate
#define MMW2(BUF, G_) do { _Pragma("unroll")                                  \
        for (int k = 0; k < 8; ++k) {                                         \
            short8 a_ = *(const short8*)&T[l16][((G_)*8 + k)*32 + quad*8];    \
            acc = __builtin_amdgcn_mfma_f32_16x16x32_bf16(a_, FR(BUF, k),     \
                                                          acc, 0, 0, 0);      \
        } } while (0)

#define EPI_T(T_) do { int col = wid*128 + (T_)*16 + l16;                     \
        _Pragma("unroll")                                                     \
        for (int r = 0; r < 4; ++r)                                           \
            T[quad*4 + r][col] = f32_to_bf16(fast_tanh(acc[r] + biasA[T_]));  \
        } while (0)

#define EPI_P(T_) do { int col = wid*128 + (T_)*16 + l16;                     \
        _Pragma("unroll")                                                     \
        for (int r = 0; r < 4; ++r) {                                         \
            float tt = bf16_to_f32(T[quad*4 + r][col]);                       \
            T[quad*4 + r][col] = f32_to_bf16((1.f - tt*tt) * acc[r]);         \
        } } while (0)

    // ---- prologue: first two W1 tiles in flight immediately
    LDW1(rawE, 0);
    LDW1(rawO, 1);

    float biasA[8];
#pragma unroll
    for (int t = 0; t < 8; ++t) biasA[t] = b1[wid*128 + t*16 + l16];
    const float bb2_0 = b2[wid*32 +  0 + l16];
    const float bb2_1 = b2[wid*32 + 16 + l16];

    // stage Y [16][256] fp32 -> bf16 (8 elems/thread)
    {
        int row = tid >> 5, col = (tid & 31) * 8;
        const float* src = &Y[(size_t)(bm + row) * D_SZ + col];
        float4 lo = *(const float4*)src;
        float4 hi = *(const float4*)(src + 4);
        *(uint4*)&Av[row][col] = pack8(lo, hi);
    }
    bar_lgkm();                                    // Av visible; 2 tiles in flight

    f32x4 acc;
    short8 a0[8];

    // ---- phase 0: t = tanh(Y @ W1^T + b1) -> T   (8 tiles/wave)
#pragma unroll
    for (int k = 0; k < 8; ++k)
        a0[k] = *(const short8*)&Av[l16][k*32 + quad*8];
    MFW1(rawE); EPI_T(0); LDW1(rawE, 2);
    MFW1(rawO); EPI_T(1); LDW1(rawO, 3);
    MFW1(rawE); EPI_T(2); LDW1(rawE, 4);
    MFW1(rawO); EPI_T(3); LDW1(rawO, 5);
    MFW1(rawE); EPI_T(4); LDW1(rawE, 6);
    MFW1(rawO); EPI_T(5); LDW1(rawO, 7);
    MFW1(rawE); EPI_T(6); LDW2(rawE, 0, 0);        // ph1 prefetch
    MFW1(rawO); EPI_T(7); LDW2(rawO, 0, 1);
    bar_lgkm();                                    // T visible

    // ---- phase 1: v = T @ W2^T + b2 -> V fp32, vb -> Av bf16  (2 tiles/wave)
    acc = (f32x4){0.f,0.f,0.f,0.f};
    MMW2(rawE, 0); LDW2(rawE, 0, 2);
    MMW2(rawO, 1); LDW2(rawO, 0, 3);
    MMW2(rawE, 2); LDW2(rawE, 1, 0);
    MMW2(rawO, 3); LDW2(rawO, 1, 1);
    {
        const int n = wid*32 + l16;
#pragma unroll
        for (int r = 0; r < 4; ++r) {
            float v = acc[r] + bb2_0;
            V[quad*4 + r][n]  = v;
            Av[quad*4 + r][n] = f32_to_bf16(v);
        }
    }
    acc = (f32x4){0.f,0.f,0.f,0.f};
    MMW2(rawE, 0); LDW2(rawE, 1, 2);
    MMW2(rawO, 1); LDW2(rawO, 1, 3);
    MMW2(rawE, 2); LDW1(rawE, 0);                  // ph2 prefetch
    MMW2(rawO, 3); LDW1(rawO, 1);
    {
        const int n = wid*32 + 16 + l16;
#pragma unroll
        for (int r = 0; r < 4; ++r) {
            float v = acc[r] + bb2_1;
            V[quad*4 + r][n]  = v;
            Av[quad*4 + r][n] = f32_to_bf16(v);
        }
    }
    bar_lgkm();                                    // V, Av(vb) visible

    // ---- phase 2: p = (1-t^2) ⊙ (vb @ W1^T) -> T (in place; 8 tiles/wave)
#pragma unroll
    for (int k = 0; k < 8; ++k)
        a0[k] = *(const short8*)&Av[l16][k*32 + quad*8];
    MFW1(rawE); EPI_P(0); LDW1(rawE, 2);
    MFW1(rawO); EPI_P(1); LDW1(rawO, 3);
    MFW1(rawE); EPI_P(2); LDW1(rawE, 4);
    MFW1(rawO); EPI_P(3); LDW1(rawO, 5);
    MFW1(rawE); EPI_P(4); LDW1(rawE, 6);
    MFW1(rawO); EPI_P(5); LDW1(rawO, 7);
    MFW1(rawE); EPI_P(6); LDW2(rawE, 0, 0);        // ph3 prefetch
    MFW1(rawO); EPI_P(7); LDW2(rawO, 0, 1);
    bar_lgkm();                                    // p visible

    // ---- phase 3: OUT = V + 0.005 * (p @ W2^T)  (2 tiles/wave)
    acc = (f32x4){0.f,0.f,0.f,0.f};
    MMW2(rawE, 0); LDW2(rawE, 0, 2);
    MMW2(rawO, 1); LDW2(rawO, 0, 3);
    MMW2(rawE, 2); LDW2(rawE, 1, 0);
    MMW2(rawO, 3); LDW2(rawO, 1, 1);
    {
        const int n = wid*32 + l16;
#pragma unroll
        for (int r = 0; r < 4; ++r) {
            const int m = quad*4 + r;
            OUT[(size_t)(bm + m) * D_SZ + n] = V[m][n] + 0.005f * acc[r];
        }
    }
    acc = (f32x4){0.f,0.f,0.f,0.f};
    MMW2(rawE, 0); LDW2(rawE, 1, 2);
    MMW2(rawO, 1); LDW2(rawO, 1, 3);
    MMW2(rawE, 2);
    MMW2(rawO, 3);
    {
        const int n = wid*32 + 16 + l16;
#pragma unroll
        for (int r = 0; r < 4; ++r) {
            const int m = quad*4 + r;
            OUT[(size_t)(bm + m) * D_SZ + n] = V[m][n] + 0.005f * acc[r];
        }
    }
#undef LDW1
#undef LDW2
#undef FR
#undef MFW1
#undef MMW2
#undef EPI_T
#undef EPI_P
}

extern "C" void kernel_launch(void* const* d_in, const int* in_sizes, int n_in,
                              void* d_out, int out_size, void* d_ws, size_t ws_size,
                              hipStream_t stream) {
    const float* Y  = (const float*)d_in[0];  // (512, 256)
    const float* W1 = (const float*)d_in[1];  // (1024, 256)
    const float* b1 = (const float*)d_in[2];  // (1024,)
    const float* W2 = (const float*)d_in[3];  // (256, 1024)
    const float* b2 = (const float*)d_in[4];  // (256,)
    float* OUT = (float*)d_out;               // (512, 256)

    fused_chain<<<32, 512, 0, stream>>>(Y, W1, b1, W2, b2, OUT);
}

// Round 6
// 101.539 us; speedup vs baseline: 1.8187x; 1.8187x over previous
//
#include <hip/hip_runtime.h>
#include <math.h>

// EulerRosenbrockModel: B=512, D=256, HID=1024, h=0.01
// out = v + 0.005 * W2 (s ⊙ (W1 vb)),  s = 1-t^2, t = tanh(W1 y + b1), v = W2 t + b2
// (Neumann truncation of (I-cJ)^{-1}(I+dJ), exact to ~1e-5 — verified R1-R12.)
//
// R13: zero-VGPR-in-flight streaming. R10/R12 post-mortem: every register-
// buffered prefetch scheme died on the 128-VGPR allocator cap (spill traffic
// in WRITE_SIZE; loads re-serialized at ~700cy each). Fix: weights stream
// global->LDS via __builtin_amdgcn_global_load_lds (outstanding loads cost
// ZERO registers; depth bounded by vmcnt, not the RF). The pre-swizzled
// fragment layout (convert_w, R10-verified) matches its semantics exactly:
// per-lane src frag*1024+lane*16 -> wave-uniform LDS slot + lane*16.
//   * 32 blocks x 1024 thr (16 waves); per-wave PRIVATE 6-slot x 1KB ring.
//   * continuous 128-frag stream (ph0 W1 / ph1 W2 / ph2 W1 / ph3 W2);
//     steady state: s_waitcnt vmcnt(5) -> ds_read_b128 -> issue frag i+6
//     into same slot -> MFMA. Literal-tail waits 5,4,3,2,1,0 at the end.
//   * prefetch crosses the lgkm-only phase barriers (slots wave-private).
//   * v kept in registers (ph1 producer lane == ph3 consumer lane) — V LDS
//     deleted. Footprint ~85 VGPR -> no spill at the 128 cap.
// Also: dispatch boundaries measured cheap (~2us); the 40us fill is the
// harness's unconditional workspace poison — not addressable from here.

#define B_SZ 512
#define D_SZ 256
#define HID_SZ 1024

typedef short short8 __attribute__((ext_vector_type(8)));   // 8 bf16 (4 VGPRs)
typedef float f32x4 __attribute__((ext_vector_type(4)));

__device__ __forceinline__ float bf16_to_f32(unsigned short u) {
    union { unsigned int i; float f; } c; c.i = ((unsigned int)u) << 16; return c.f;
}
__device__ __forceinline__ unsigned short f32_to_bf16(float f) {
    union { float f; unsigned int i; } c; c.f = f;
    unsigned int b = c.i + 0x7FFFu + ((c.i >> 16) & 1u);   // RNE
    return (unsigned short)(b >> 16);
}
__device__ __forceinline__ uint4 pack8(float4 lo, float4 hi) {
    union { unsigned short u[8]; uint4 v; } o;
    o.u[0] = f32_to_bf16(lo.x); o.u[1] = f32_to_bf16(lo.y);
    o.u[2] = f32_to_bf16(lo.z); o.u[3] = f32_to_bf16(lo.w);
    o.u[4] = f32_to_bf16(hi.x); o.u[5] = f32_to_bf16(hi.y);
    o.u[6] = f32_to_bf16(hi.z); o.u[7] = f32_to_bf16(hi.w);
    return o.v;
}
__device__ __forceinline__ float fast_tanh(float x) {
    float e = __expf(2.0f * x);
    return 1.0f - 2.0f / (e + 1.0f);
}
// lgkm-drain barrier: cross-wave LDS visibility WITHOUT draining vmcnt —
// global(_load_lds) ops stay in flight across it (R9/R11-verified).
__device__ __forceinline__ void bar_lgkm() {
    asm volatile("s_waitcnt lgkmcnt(0)" ::: "memory");
    __builtin_amdgcn_s_barrier();
    asm volatile("" ::: "memory");
}
template<int N>
__device__ __forceinline__ void wait_vmcnt() {
    asm volatile("s_waitcnt vmcnt(%0)" :: "n"(N) : "memory");
}
__device__ __forceinline__ void gload_lds16(const uint4* g, uint4* lds) {
    __builtin_amdgcn_global_load_lds(
        (const __attribute__((address_space(1))) void*)g,
        (__attribute__((address_space(3))) void*)lds,
        16, 0, 0);
}

// ---- D1: swizzle weights into fragment order, fp32 -> bf16 (R10-verified).
// W1s: frag f1 = t1*8 + ks8   (t1 in [0,64), ks8 in [0,8))
//      lane l: W1[t1*16 + (l&15)][ks8*32 + (l>>4)*8 .. +8]  at f1*1024 + l*16
// W2s: frag f2 = t2*32 + ks8  (t2 in [0,16), ks8 in [0,32))
//      lane l: W2[t2*16 + (l&15)][ks8*32 + (l>>4)*8 .. +8]  at f2*1024 + l*16
__global__ __launch_bounds__(256)
void convert_w(const float* __restrict__ W1, const float* __restrict__ W2,
               uint4* __restrict__ W1s, uint4* __restrict__ W2s)
{
    const int wid  = threadIdx.x >> 6, lane = threadIdx.x & 63;
    const int l16  = lane & 15, quad = lane >> 4;
    const int frag = blockIdx.x * 4 + wid;         // 0..1023
    const float* src;
    uint4* dst;
    if (frag < 512) {
        int t1 = frag >> 3, ks8 = frag & 7;
        src = &W1[(size_t)(t1 * 16 + l16) * D_SZ + ks8 * 32 + quad * 8];
        dst = &W1s[(size_t)frag * 64 + lane];
    } else {
        int f2 = frag - 512;
        int t2 = f2 >> 5, ks8 = f2 & 31;
        src = &W2[(size_t)(t2 * 16 + l16) * HID_SZ + ks8 * 32 + quad * 8];
        dst = &W2s[(size_t)f2 * 64 + lane];
    }
    float4 lo = *(const float4*)src;
    float4 hi = *(const float4*)(src + 4);
    *dst = pack8(lo, hi);
}

// ---- D2: fused chain. 32 blocks x 1024 thr (16 waves), 16 rows/block.
// ph0/ph2: wave owns 4 hid tiles (cols wid*64..+64).
// ph1/ph3: wave owns 1 out tile (cols wid*16..+16), K=1024 (32 frags).
__global__ __launch_bounds__(1024)
void fused_chain(const float* __restrict__ Y,
                 const uint4* __restrict__ W1s,
                 const uint4* __restrict__ W2s,
                 const float* __restrict__ b1,
                 const float* __restrict__ b2,
                 float* __restrict__ OUT)
{
    __shared__ alignas(16) uint4 Wbuf[16 * 6 * 64];        // 96.0 KB: 16 waves x 6 slots x 1KB
    __shared__ alignas(16) unsigned short Av[16][264];     //  8.3 KB: Y bf16, then vb
    __shared__ alignas(16) unsigned short T[16][1032];     // 32.3 KB: t, then p   (136.5 KB)

    const int tid  = threadIdx.x;
    const int wid  = tid >> 6, lane = tid & 63;            // wid 0..15
    const int l16  = lane & 15, quad = lane >> 4;
    const int bm   = blockIdx.x * 16;

    // frag i (0..127) -> per-lane global source address
    auto frag_src = [&](int i) -> const uint4* {
        const int j = i & 31;
        if (((i >> 5) & 1) == 0) {                          // ph0/ph2: W1
            const int f1 = (wid * 4 + (j >> 3)) * 8 + (j & 7);
            return W1s + (size_t)f1 * 64 + lane;
        } else {                                            // ph1/ph3: W2
            const int f2 = wid * 32 + j;
            return W2s + (size_t)f2 * 64 + lane;
        }
    };

    // stage Y [16][256] fp32 -> bf16: thread handles 4 floats (row wid, col lane*4)
    {
        const int row = tid >> 6, c4 = (tid & 63) * 4;
        float4 yv = *(const float4*)&Y[(size_t)(bm + row) * D_SZ + c4];
        union { unsigned short u[4]; uint2 v; } o;
        o.u[0] = f32_to_bf16(yv.x); o.u[1] = f32_to_bf16(yv.y);
        o.u[2] = f32_to_bf16(yv.z); o.u[3] = f32_to_bf16(yv.w);
        *(uint2*)&Av[row][c4] = o.v;
    }
    float biasA[4];
#pragma unroll
    for (int t = 0; t < 4; ++t) biasA[t] = b1[wid * 64 + t * 16 + l16];
    const float bb2 = b2[wid * 16 + l16];
    wait_vmcnt<0>();        // drain Y/bias loads: vmcnt bookkeeping starts clean

    // prologue: 6 fragments in flight (slots 0..5)
#pragma unroll
    for (int s = 0; s < 6; ++s)
        gload_lds16(frag_src(s), &Wbuf[(wid * 6 + s) * 64]);

    bar_lgkm();             // Av visible to all waves; frags stay in flight

    short8 a0[8];
#pragma unroll
    for (int k = 0; k < 8; ++k)
        a0[k] = *(const short8*)&Av[l16][k * 32 + quad * 8];

    f32x4 acc = {0.f, 0.f, 0.f, 0.f};

    // ---- phase 0: t = tanh(Y @ W1^T + b1) -> T   (frags 0..31)
#pragma unroll
    for (int j = 0; j < 32; ++j) {
        wait_vmcnt<5>();                                    // frag j landed
        short8 b = *(const short8*)&Wbuf[(wid * 6 + (j % 6)) * 64 + lane];
        __builtin_amdgcn_sched_barrier(0);                  // read before slot reuse
        gload_lds16(frag_src(j + 6), &Wbuf[(wid * 6 + (j % 6)) * 64]);
        acc = __builtin_amdgcn_mfma_f32_16x16x32_bf16(a0[j & 7], b, acc, 0, 0, 0);
        if ((j & 7) == 7) {
            const int tt = j >> 3;
            const int col = wid * 64 + tt * 16 + l16;
#pragma unroll
            for (int r = 0; r < 4; ++r)
                T[quad * 4 + r][col] = f32_to_bf16(fast_tanh(acc[r] + biasA[tt]));
            acc = (f32x4){0.f, 0.f, 0.f, 0.f};
        }
    }
    bar_lgkm();             // T visible

    // ---- phase 1: v = T @ W2^T + b2 (frags 32..63; one out-tile, K=1024)
#pragma unroll
    for (int j = 0; j < 32; ++j) {
        const int i = 32 + j;
        wait_vmcnt<5>();
        short8 b = *(const short8*)&Wbuf[(wid * 6 + (i % 6)) * 64 + lane];
        short8 a = *(const short8*)&T[l16][j * 32 + quad * 8];
        __builtin_amdgcn_sched_barrier(0);
        gload_lds16(frag_src(i + 6), &Wbuf[(wid * 6 + (i % 6)) * 64]);
        acc = __builtin_amdgcn_mfma_f32_16x16x32_bf16(a, b, acc, 0, 0, 0);
    }
    float vkeep[4];
    {
        const int n = wid * 16 + l16;
#pragma unroll
        for (int r = 0; r < 4; ++r) {
            float v = acc[r] + bb2;
            vkeep[r] = v;                                   // ph3 consumer = same lane
            Av[quad * 4 + r][n] = f32_to_bf16(v);           // vb for ph2
        }
        acc = (f32x4){0.f, 0.f, 0.f, 0.f};
    }
    bar_lgkm();             // vb visible

    // ---- phase 2: p = (1-t^2) ⊙ (vb @ W1^T) -> T in place (frags 64..95)
#pragma unroll
    for (int k = 0; k < 8; ++k)
        a0[k] = *(const short8*)&Av[l16][k * 32 + quad * 8];
#pragma unroll
    for (int j = 0; j < 32; ++j) {
        const int i = 64 + j;
        wait_vmcnt<5>();
        short8 b = *(const short8*)&Wbuf[(wid * 6 + (i % 6)) * 64 + lane];
        __builtin_amdgcn_sched_barrier(0);
        gload_lds16(frag_src(i + 6), &Wbuf[(wid * 6 + (i % 6)) * 64]);
        acc = __builtin_amdgcn_mfma_f32_16x16x32_bf16(a0[j & 7], b, acc, 0, 0, 0);
        if ((j & 7) == 7) {
            const int tt = j >> 3;
            const int col = wid * 64 + tt * 16 + l16;
#pragma unroll
            for (int r = 0; r < 4; ++r) {
                float t_ = bf16_to_f32(T[quad * 4 + r][col]);
                T[quad * 4 + r][col] = f32_to_bf16((1.f - t_ * t_) * acc[r]);
            }
            acc = (f32x4){0.f, 0.f, 0.f, 0.f};
        }
    }
    bar_lgkm();             // p visible

    // ---- phase 3: OUT = v + 0.005 * (p @ W2^T)  (frags 96..127)
#pragma unroll
    for (int j = 0; j < 26; ++j) {                          // last issue: frag 127
        const int i = 96 + j;
        wait_vmcnt<5>();
        short8 b = *(const short8*)&Wbuf[(wid * 6 + (i % 6)) * 64 + lane];
        short8 a = *(const short8*)&T[l16][j * 32 + quad * 8];
        __builtin_amdgcn_sched_barrier(0);
        gload_lds16(frag_src(i + 6), &Wbuf[(wid * 6 + (i % 6)) * 64]);
        acc = __builtin_amdgcn_mfma_f32_16x16x32_bf16(a, b, acc, 0, 0, 0);
    }
    // tail: nothing left to issue; literal waits drain the ring
#define TAIL(J, W) do {                                                        \
        wait_vmcnt<W>();                                                       \
        short8 b = *(const short8*)&Wbuf[(wid * 6 + ((96 + (J)) % 6)) * 64 + lane]; \
        short8 a = *(const short8*)&T[l16][(J) * 32 + quad * 8];               \
        acc = __builtin_amdgcn_mfma_f32_16x16x32_bf16(a, b, acc, 0, 0, 0);     \
    } while (0)
    TAIL(26, 5); TAIL(27, 4); TAIL(28, 3); TAIL(29, 2); TAIL(30, 1); TAIL(31, 0);
#undef TAIL
    {
        const int n = wid * 16 + l16;
#pragma unroll
        for (int r = 0; r < 4; ++r)
            OUT[(size_t)(bm + quad * 4 + r) * D_SZ + n] = vkeep[r] + 0.005f * acc[r];
    }
}

extern "C" void kernel_launch(void* const* d_in, const int* in_sizes, int n_in,
                              void* d_out, int out_size, void* d_ws, size_t ws_size,
                              hipStream_t stream) {
    const float* Y  = (const float*)d_in[0];  // (512, 256)
    const float* W1 = (const float*)d_in[1];  // (1024, 256)
    const float* b1 = (const float*)d_in[2];  // (1024,)
    const float* W2 = (const float*)d_in[3];  // (256, 1024)
    const float* b2 = (const float*)d_in[4];  // (256,)
    float* OUT = (float*)d_out;               // (512, 256)

    uint4* W1s = (uint4*)d_ws;                       // 512 frags x 1KB = 512 KB
    uint4* W2s = W1s + (size_t)512 * 64;             // 512 frags x 1KB = 512 KB

    convert_w<<<256, 256, 0, stream>>>(W1, W2, W1s, W2s);
    fused_chain<<<32, 1024, 0, stream>>>(Y, W1s, W2s, b1, b2, OUT);
}

// Round 7
// 79.540 us; speedup vs baseline: 2.3218x; 1.2766x over previous
//
#include <hip/hip_runtime.h>
#include <math.h>

// EulerRosenbrockModel: B=512, D=256, HID=1024, h=0.01
// out = v + 0.005 * W2 (s ⊙ (W1 vb)),  s = 1-t^2, t = tanh(W1 y + b1), v = W2 t + b2
// (Neumann truncation of (I-cJ)^{-1}(I+dJ), exact to ~1e-5 — verified R1-R13.)
//
// R14: de-correlated weight streams. R13 post-mortem: fused=43.5us = 20 B/cy/CU
// with 96KB/CU outstanding -> the SERVER (XCD L2) is the limit, not in-flight
// depth. All co-XCD CUs read the identical 1MB stream in the same order at the
// same pace -> narrow live window -> few L2 banks serve 4 CUs each. Fixes:
//   * per-block stream ROTATION: co-XCD blocks {b,b+8,b+16,b+24} get rot=0..3;
//     ph0/ph2 tile order and ph1/ph3 K-group order rotated so the 4 CUs of an
//     XCD read disjoint regions at any instant (accumulation reorder only).
//   * fragments load DIRECTLY global->VGPR (bf16 frag = 4 VGPR; two 4-frag
//     buffers = 32 VGPR; total ~100 < 128 cap -> no spill, unlike R11/R12).
//     Avoids the LDS-DMA path's possible ~20B/cy engine cap too.
//   * v kept in registers (R13 vkeep trick) -> V LDS deleted (LDS 40.6 KB).
// Weights pre-swizzled to fragment order by convert_w (R10-verified): frag =
// 1KB contiguous, lane l's 16B at l*16.

#define B_SZ 512
#define D_SZ 256
#define HID_SZ 1024

typedef short short8 __attribute__((ext_vector_type(8)));   // 8 bf16 (4 VGPRs)
typedef float f32x4 __attribute__((ext_vector_type(4)));

__device__ __forceinline__ float bf16_to_f32(unsigned short u) {
    union { unsigned int i; float f; } c; c.i = ((unsigned int)u) << 16; return c.f;
}
__device__ __forceinline__ unsigned short f32_to_bf16(float f) {
    union { float f; unsigned int i; } c; c.f = f;
    unsigned int b = c.i + 0x7FFFu + ((c.i >> 16) & 1u);   // RNE
    return (unsigned short)(b >> 16);
}
__device__ __forceinline__ uint4 pack8(float4 lo, float4 hi) {
    union { unsigned short u[8]; uint4 v; } o;
    o.u[0] = f32_to_bf16(lo.x); o.u[1] = f32_to_bf16(lo.y);
    o.u[2] = f32_to_bf16(lo.z); o.u[3] = f32_to_bf16(lo.w);
    o.u[4] = f32_to_bf16(hi.x); o.u[5] = f32_to_bf16(hi.y);
    o.u[6] = f32_to_bf16(hi.z); o.u[7] = f32_to_bf16(hi.w);
    return o.v;
}
__device__ __forceinline__ float fast_tanh(float x) {
    float e = __expf(2.0f * x);
    return 1.0f - 2.0f / (e + 1.0f);
}
__device__ __forceinline__ short8 as_short8(uint4 u) {
    union { uint4 v; short8 s; } c; c.v = u; return c.s;
}
// lgkm-drain barrier: cross-wave LDS visibility WITHOUT draining vmcnt —
// global loads stay in flight across it (R9/R11/R13-verified).
__device__ __forceinline__ void bar_lgkm() {
    asm volatile("s_waitcnt lgkmcnt(0)" ::: "memory");
    __builtin_amdgcn_s_barrier();
    asm volatile("" ::: "memory");
}

// ---- D1: swizzle weights into fragment order, fp32 -> bf16 (R10-verified).
// W1s: frag f1 = t1*8 + ks8   (t1 in [0,64), ks8 in [0,8))
//      lane l: W1[t1*16 + (l&15)][ks8*32 + (l>>4)*8 .. +8]  at f1*1024 + l*16
// W2s: frag f2 = t2*32 + ks8  (t2 in [0,16), ks8 in [0,32))
//      lane l: W2[t2*16 + (l&15)][ks8*32 + (l>>4)*8 .. +8]  at f2*1024 + l*16
__global__ __launch_bounds__(256)
void convert_w(const float* __restrict__ W1, const float* __restrict__ W2,
               uint4* __restrict__ W1s, uint4* __restrict__ W2s)
{
    const int wid  = threadIdx.x >> 6, lane = threadIdx.x & 63;
    const int l16  = lane & 15, quad = lane >> 4;
    const int frag = blockIdx.x * 4 + wid;         // 0..1023
    const float* src;
    uint4* dst;
    if (frag < 512) {
        int t1 = frag >> 3, ks8 = frag & 7;
        src = &W1[(size_t)(t1 * 16 + l16) * D_SZ + ks8 * 32 + quad * 8];
        dst = &W1s[(size_t)frag * 64 + lane];
    } else {
        int f2 = frag - 512;
        int t2 = f2 >> 5, ks8 = f2 & 31;
        src = &W2[(size_t)(t2 * 16 + l16) * HID_SZ + ks8 * 32 + quad * 8];
        dst = &W2s[(size_t)f2 * 64 + lane];
    }
    float4 lo = *(const float4*)src;
    float4 hi = *(const float4*)(src + 4);
    *dst = pack8(lo, hi);
}

// ---- D2: fused chain. 32 blocks x 1024 thr (16 waves), 16 rows/block.
// ph0/ph2: wave owns 4 hid tiles (cols wid*64..+64), tile order rotated.
// ph1/ph3: wave owns 1 out tile (cols wid*16..+16), K=1024, k-groups rotated.
__global__ __launch_bounds__(1024)
void fused_chain(const float* __restrict__ Y,
                 const uint4* __restrict__ W1s,
                 const uint4* __restrict__ W2s,
                 const float* __restrict__ b1,
                 const float* __restrict__ b2,
                 float* __restrict__ OUT)
{
    __shared__ alignas(16) unsigned short Av[16][264];     //  8.3 KB: Y bf16, then vb
    __shared__ alignas(16) unsigned short T[16][1032];     // 32.3 KB: t, then p  (40.6 KB)

    const int tid  = threadIdx.x;
    const int wid  = tid >> 6, lane = tid & 63;            // wid 0..15
    const int l16  = lane & 15, quad = lane >> 4;
    const int bm   = blockIdx.x * 16;
    const int rot  = (blockIdx.x >> 3) & 3;                // co-XCD blocks get 0..3

    uint4 bE[4], bO[4];          // two 4-frag buffers (16+16 VGPR)

    // ph0/ph2 unit U (0..7): rotated tile ta=((U>>1)+rot)&3, frags k0=(U&1)*4 ..+4
#define LDU1(BUF, U) do {                                                     \
        const int ta_ = (((U) >> 1) + rot) & 3;                               \
        const uint4* p_ = W1s + ((size_t)((wid * 4 + ta_) * 8 + ((U) & 1) * 4)) * 64 + lane; \
        _Pragma("unroll") for (int i = 0; i < 4; ++i) BUF[i] = p_[i * 64];    \
    } while (0)

    // ph1/ph3 unit U (0..7): rotated k-group kk0=((U)*4+8*rot)&31, frags kk0..+4
#define LDU2(BUF, U) do {                                                     \
        const int kk_ = (((U) * 4 + 8 * rot) & 31);                           \
        const uint4* p_ = W2s + ((size_t)(wid * 32 + kk_)) * 64 + lane;       \
        _Pragma("unroll") for (int i = 0; i < 4; ++i) BUF[i] = p_[i * 64];    \
    } while (0)

#define MF1(BUF, U) do { _Pragma("unroll")                                    \
        for (int i = 0; i < 4; ++i)                                           \
            acc = __builtin_amdgcn_mfma_f32_16x16x32_bf16(                    \
                    a0[((U) & 1) * 4 + i], as_short8(BUF[i]), acc, 0, 0, 0);  \
    } while (0)

#define MF2(BUF, U) do { const int kk0_ = (((U) * 4 + 8 * rot) & 31);         \
        _Pragma("unroll")                                                     \
        for (int i = 0; i < 4; ++i) {                                         \
            short8 a_ = *(const short8*)&T[l16][(kk0_ + i) * 32 + quad * 8];  \
            acc = __builtin_amdgcn_mfma_f32_16x16x32_bf16(                    \
                    a_, as_short8(BUF[i]), acc, 0, 0, 0);                     \
        } } while (0)

    // epilogue after odd unit U completes rotated tile (U>>1)
#define EPI_T(U) do { const int ta_ = (((U) >> 1) + rot) & 3;                 \
        const int col = wid * 64 + ta_ * 16 + l16;                            \
        _Pragma("unroll")                                                     \
        for (int r = 0; r < 4; ++r)                                           \
            T[quad * 4 + r][col] = f32_to_bf16(fast_tanh(acc[r] + biasT[(U) >> 1])); \
        acc = (f32x4){0.f, 0.f, 0.f, 0.f};                                    \
    } while (0)

#define EPI_P(U) do { const int ta_ = (((U) >> 1) + rot) & 3;                 \
        const int col = wid * 64 + ta_ * 16 + l16;                            \
        _Pragma("unroll")                                                     \
        for (int r = 0; r < 4; ++r) {                                         \
            float t_ = bf16_to_f32(T[quad * 4 + r][col]);                     \
            T[quad * 4 + r][col] = f32_to_bf16((1.f - t_ * t_) * acc[r]);     \
        }                                                                     \
        acc = (f32x4){0.f, 0.f, 0.f, 0.f};                                    \
    } while (0)

    // ---- prologue: first two ph0 units in flight immediately
    LDU1(bE, 0);
    LDU1(bO, 1);

    // biases in rotated-tile order (static indices only)
    float biasT[4];
#pragma unroll
    for (int t = 0; t < 4; ++t)
        biasT[t] = b1[wid * 64 + (((t + rot) & 3) * 16) + l16];
    const float bb2 = b2[wid * 16 + l16];

    // stage Y [16][256] fp32 -> bf16: row = tid>>6, 4 floats per thread
    {
        const int row = tid >> 6, c4 = (tid & 63) * 4;
        float4 yv = *(const float4*)&Y[(size_t)(bm + row) * D_SZ + c4];
        union { unsigned short u[4]; uint2 v; } o;
        o.u[0] = f32_to_bf16(yv.x); o.u[1] = f32_to_bf16(yv.y);
        o.u[2] = f32_to_bf16(yv.z); o.u[3] = f32_to_bf16(yv.w);
        *(uint2*)&Av[row][c4] = o.v;
    }
    bar_lgkm();                                    // Av visible; weights in flight

    f32x4 acc = {0.f, 0.f, 0.f, 0.f};
    short8 a0[8];

    // ---- phase 0: t = tanh(Y @ W1^T + b1) -> T
#pragma unroll
    for (int k = 0; k < 8; ++k)
        a0[k] = *(const short8*)&Av[l16][k * 32 + quad * 8];
    MF1(bE, 0); LDU1(bE, 2);
    MF1(bO, 1); LDU1(bO, 3); EPI_T(1);
    MF1(bE, 2); LDU1(bE, 4);
    MF1(bO, 3); LDU1(bO, 5); EPI_T(3);
    MF1(bE, 4); LDU1(bE, 6);
    MF1(bO, 5); LDU1(bO, 7); EPI_T(5);
    MF1(bE, 6); LDU2(bE, 0);                       // ph1 prefetch
    MF1(bO, 7); LDU2(bO, 1); EPI_T(7);
    bar_lgkm();                                    // T visible

    // ---- phase 1: v = T @ W2^T + b2 (kept in regs) ; vb -> Av
    MF2(bE, 0); LDU2(bE, 2);
    MF2(bO, 1); LDU2(bO, 3);
    MF2(bE, 2); LDU2(bE, 4);
    MF2(bO, 3); LDU2(bO, 5);
    MF2(bE, 4); LDU2(bE, 6);
    MF2(bO, 5); LDU2(bO, 7);
    MF2(bE, 6); LDU1(bE, 0);                       // ph2 prefetch
    MF2(bO, 7); LDU1(bO, 1);
    float vkeep[4];
    {
        const int n = wid * 16 + l16;
#pragma unroll
        for (int r = 0; r < 4; ++r) {
            float v = acc[r] + bb2;
            vkeep[r] = v;                          // ph3 consumer = same lane
            Av[quad * 4 + r][n] = f32_to_bf16(v);  // vb for ph2
        }
        acc = (f32x4){0.f, 0.f, 0.f, 0.f};
    }
    bar_lgkm();                                    // vb visible

    // ---- phase 2: p = (1-t^2) ⊙ (vb @ W1^T) -> T in place
#pragma unroll
    for (int k = 0; k < 8; ++k)
        a0[k] = *(const short8*)&Av[l16][k * 32 + quad * 8];
    MF1(bE, 0); LDU1(bE, 2);
    MF1(bO, 1); LDU1(bO, 3); EPI_P(1);
    MF1(bE, 2); LDU1(bE, 4);
    MF1(bO, 3); LDU1(bO, 5); EPI_P(3);
    MF1(bE, 4); LDU1(bE, 6);
    MF1(bO, 5); LDU1(bO, 7); EPI_P(5);
    MF1(bE, 6); LDU2(bE, 0);                       // ph3 prefetch
    MF1(bO, 7); LDU2(bO, 1); EPI_P(7);
    bar_lgkm();                                    // p visible

    // ---- phase 3: OUT = v + 0.005 * (p @ W2^T)
    MF2(bE, 0); LDU2(bE, 2);
    MF2(bO, 1); LDU2(bO, 3);
    MF2(bE, 2); LDU2(bE, 4);
    MF2(bO, 3); LDU2(bO, 5);
    MF2(bE, 4); LDU2(bE, 6);
    MF2(bO, 5); LDU2(bO, 7);
    MF2(bE, 6);
    MF2(bO, 7);
    {
        const int n = wid * 16 + l16;
#pragma unroll
        for (int r = 0; r < 4; ++r)
            OUT[(size_t)(bm + quad * 4 + r) * D_SZ + n] = vkeep[r] + 0.005f * acc[r];
    }
#undef LDU1
#undef LDU2
#undef MF1
#undef MF2
#undef EPI_T
#undef EPI_P
}

extern "C" void kernel_launch(void* const* d_in, const int* in_sizes, int n_in,
                              void* d_out, int out_size, void* d_ws, size_t ws_size,
                              hipStream_t stream) {
    const float* Y  = (const float*)d_in[0];  // (512, 256)
    const float* W1 = (const float*)d_in[1];  // (1024, 256)
    const float* b1 = (const float*)d_in[2];  // (1024,)
    const float* W2 = (const float*)d_in[3];  // (256, 1024)
    const float* b2 = (const float*)d_in[4];  // (256,)
    float* OUT = (float*)d_out;               // (512, 256)

    uint4* W1s = (uint4*)d_ws;                       // 512 frags x 1KB = 512 KB
    uint4* W2s = W1s + (size_t)512 * 64;             // 512 frags x 1KB = 512 KB

    convert_w<<<256, 256, 0, stream>>>(W1, W2, W1s, W2s);
    fused_chain<<<32, 1024, 0, stream>>>(Y, W1s, W2s, b1, b2, OUT);
}